// Round 13
// baseline (342.851 us; speedup 1.0000x reference)
//
#include <hip/hip_runtime.h>
#include <hip/hip_bf16.h>
#include <math.h>

// Problem constants
#define BB 2
#define SS 2048
#define EE 768
#define HH 12
#define DD 64
#define FF 3072
#define BSROWS (BB*SS)      // 4096
#define HD (HH*DD)          // 768

typedef __hip_bfloat16 bf16;
typedef __attribute__((ext_vector_type(8))) short short8;
typedef __attribute__((ext_vector_type(4))) float f32x4;

__device__ inline void store_val(float* p, float v) { *p = v; }
__device__ inline void store_val(bf16* p, float v)  { *p = __float2bfloat16(v); }

// ---------------------------------------------------------------------------
// All 6 weight transposes (f32 -> bf16, [R,C] -> [C,R] per z-slice) in ONE
// kernel. 32x32 tiles; blockIdx.x decoded against compile-time tile ranges.
// ---------------------------------------------------------------------------
__global__ __launch_bounds__(256)
void transpose_all(const float* __restrict__ Wq, const float* __restrict__ Wv,
                   const float* __restrict__ Wo, const float* __restrict__ W1,
                   const float* __restrict__ W2, const float* __restrict__ W3,
                   bf16* __restrict__ WqT, bf16* __restrict__ WvT,
                   bf16* __restrict__ WoT, bf16* __restrict__ W1T,
                   bf16* __restrict__ W2T, bf16* __restrict__ W3T)
{
    const int id = blockIdx.x;
    const float* in; bf16* out; int R, C, z = 0, local;
    if (id < 1152) {                       // Wq / Wv: 12 slices of [768, 64]
        const bool isv = id >= 576;
        local = isv ? id - 576 : id;
        in = isv ? Wv : Wq; out = isv ? WvT : WqT;
        R = EE; C = DD;
        z = local / 48; local -= z * 48;
    } else if (id < 1728)  { in = Wo; out = WoT; R = HD; C = EE; local = id - 1152; }
    else if (id < 4032)    { in = W1; out = W1T; R = EE; C = FF; local = id - 1728; }
    else if (id < 13248)   { in = W2; out = W2T; R = FF; C = FF; local = id - 4032; }
    else                   { in = W3; out = W3T; R = FF; C = EE; local = id - 13248; }
    const int tiles_x = C >> 5;
    const int ty = local / tiles_x, tx = local - ty * tiles_x;
    const int r0 = ty * 32, c0 = tx * 32;
    const size_t zoff = (size_t)z * R * C;

    __shared__ float tile[32][33];
    const int t = threadIdx.x;
    const int lr = t >> 5, lc = t & 31;
    #pragma unroll
    for (int i = 0; i < 4; ++i)
        tile[lr + 8 * i][lc] = in[zoff + (size_t)(r0 + lr + 8 * i) * C + c0 + lc];
    __syncthreads();
    #pragma unroll
    for (int i = 0; i < 4; ++i)
        out[zoff + (size_t)(c0 + lr + 8 * i) * R + r0 + lc] =
            __float2bfloat16(tile[lc][lr + 8 * i]);
}

// ---------------------------------------------------------------------------
// LayerNorm: one block (256 thr) per row of 768; f32 in, OutT out
// ---------------------------------------------------------------------------
template<typename OutT>
__global__ __launch_bounds__(256)
void ln_kernel(const float* __restrict__ x, const float* __restrict__ g,
               const float* __restrict__ bt, OutT* __restrict__ o)
{
    const int row = blockIdx.x;
    const float* xr = x + (size_t)row * EE;
    const int t = threadIdx.x;
    float v0 = xr[t], v1 = xr[t + 256], v2 = xr[t + 512];
    float s = v0 + v1 + v2;
    #pragma unroll
    for (int off = 32; off > 0; off >>= 1) s += __shfl_xor(s, off);
    __shared__ float red[8];
    const int w = t >> 6;
    if ((t & 63) == 0) red[w] = s;
    __syncthreads();
    const float mean = (red[0] + red[1] + red[2] + red[3]) * (1.f / 768.f);
    float d0 = v0 - mean, d1 = v1 - mean, d2 = v2 - mean;
    float q = d0 * d0 + d1 * d1 + d2 * d2;
    #pragma unroll
    for (int off = 32; off > 0; off >>= 1) q += __shfl_xor(q, off);
    if ((t & 63) == 0) red[4 + w] = q;
    __syncthreads();
    const float var = (red[4] + red[5] + red[6] + red[7]) * (1.f / 768.f);
    const float rstd = rsqrtf(var + 1e-5f);
    OutT* orow = o + (size_t)row * EE;
    store_val(&orow[t],       d0 * rstd * g[t]       + bt[t]);
    store_val(&orow[t + 256], d1 * rstd * g[t + 256] + bt[t + 256]);
    store_val(&orow[t + 512], d2 * rstd * g[t + 512] + bt[t + 512]);
}

// ---------------------------------------------------------------------------
// bf16 MFMA GEMM (m97 structure): C[M,N] = A[M,K] @ Bt[N,K]^T + bias (+res)
// 128x128 tile, BK=64, 4 waves (2x2). Used for O-proj and FF3.
// ---------------------------------------------------------------------------
template<typename OutT, bool RELU, bool HAS_RES, bool VT = false>
__global__ __launch_bounds__(256, 2)
void mfma_gemm(const bf16* __restrict__ A, const bf16* __restrict__ Bt,
               const float* __restrict__ bias, const float* __restrict__ res,
               OutT* __restrict__ C, int M, int N, int K)
{
    __shared__ bf16 As[128 * 64];
    __shared__ bf16 Bs[128 * 64];
    const int t = threadIdx.x;
    const int lane = t & 63;
    const int w = t >> 6;
    const int wm = w >> 1, wn = w & 1;
    const int m0 = blockIdx.y * 128, n0 = blockIdx.x * 128;
    const int fr = lane & 15;
    const int fq = lane >> 4;

    f32x4 acc[4][4];
    #pragma unroll
    for (int i = 0; i < 4; ++i)
        #pragma unroll
        for (int j = 0; j < 4; ++j)
            acc[i][j] = (f32x4){0.f, 0.f, 0.f, 0.f};

    for (int k0 = 0; k0 < K; k0 += 64) {
        asm volatile("s_waitcnt lgkmcnt(0)" ::: "memory");
        __syncthreads();
        #pragma unroll
        for (int i = 0; i < 4; ++i) {
            const int p = (w * 4 + i) * 64 + lane;
            const int m = p >> 3;
            const int c = (p & 7) ^ (m & 7);
            const bf16* ga = &A [(size_t)(m0 + m) * K + k0 + c * 8];
            const bf16* gb = &Bt[(size_t)(n0 + m) * K + k0 + c * 8];
            bf16* la = &As[(size_t)(w * 4 + i) * 512];
            bf16* lb = &Bs[(size_t)(w * 4 + i) * 512];
            __builtin_amdgcn_global_load_lds(
                (const __attribute__((address_space(1))) unsigned int*)ga,
                (__attribute__((address_space(3))) unsigned int*)la, 16, 0, 0);
            __builtin_amdgcn_global_load_lds(
                (const __attribute__((address_space(1))) unsigned int*)gb,
                (__attribute__((address_space(3))) unsigned int*)lb, 16, 0, 0);
        }
        asm volatile("s_waitcnt vmcnt(0)" ::: "memory");
        __syncthreads();

        short8 af[4][2], bfr[4][2];
        #pragma unroll
        for (int mi = 0; mi < 4; ++mi) {
            const int row = wm * 64 + mi * 16 + fr;
            #pragma unroll
            for (int kh = 0; kh < 2; ++kh) {
                const int slot = (kh * 4 + fq) ^ (row & 7);
                af[mi][kh] = *(const short8*)&As[row * 64 + slot * 8];
            }
        }
        #pragma unroll
        for (int ni = 0; ni < 4; ++ni) {
            const int row = wn * 64 + ni * 16 + fr;
            #pragma unroll
            for (int kh = 0; kh < 2; ++kh) {
                const int slot = (kh * 4 + fq) ^ (row & 7);
                bfr[ni][kh] = *(const short8*)&Bs[row * 64 + slot * 8];
            }
        }
        #pragma unroll
        for (int mi = 0; mi < 4; ++mi)
            #pragma unroll
            for (int ni = 0; ni < 4; ++ni) {
                acc[mi][ni] = __builtin_amdgcn_mfma_f32_16x16x32_bf16(
                    af[mi][0], bfr[ni][0], acc[mi][ni], 0, 0, 0);
                acc[mi][ni] = __builtin_amdgcn_mfma_f32_16x16x32_bf16(
                    af[mi][1], bfr[ni][1], acc[mi][ni], 0, 0, 0);
            }
    }

    // epilogue: C/D layout col=lane&15, row=(lane>>4)*4+reg  [m89/m91]
    #pragma unroll
    for (int ni = 0; ni < 4; ++ni) {
        const int cn = n0 + wn * 64 + ni * 16 + fr;
        const float bv = bias[cn];
        #pragma unroll
        for (int mi = 0; mi < 4; ++mi) {
            const int rbase = m0 + wm * 64 + mi * 16 + fq * 4;
            if (VT) {
                const int bidx = rbase >> 11, sidx = rbase & (SS - 1);
                const int hh = cn >> 6, dd = cn & 63;
                alignas(8) bf16 tmp[4];
                #pragma unroll
                for (int j = 0; j < 4; ++j)
                    tmp[j] = __float2bfloat16(acc[mi][ni][j] + bv);
                *(ushort4*)((bf16*)C + (((size_t)(bidx * HH + hh) * 64 + dd) * SS + sidx))
                    = *(const ushort4*)tmp;
            } else {
                #pragma unroll
                for (int j = 0; j < 4; ++j) {
                    float v = acc[mi][ni][j] + bv;
                    if (HAS_RES) v += res[(size_t)(rbase + j) * N + cn];
                    if (RELU) v = fmaxf(v, 0.f);
                    store_val(&C[(size_t)(rbase + j) * N + cn], v);
                }
            }
        }
    }
}

// ---------------------------------------------------------------------------
// 8-phase 256x256 bf16 MFMA GEMM (HK-template port) for the FF layers.
// BK=64, 8 waves (2M x 4N, 512 thr), per-wave 128x64 out. LDS 128 KiB:
// 2 dbuf x (A 256x64 + B 256x64). Per iteration: 2 K-tiles, 8 phases; each
// phase = {12 ds_read_b128; 1 stage-unit (2 gload_lds/thr); barrier;
// lgkmcnt(0); 16 MFMA (one C-quadrant x K=64); barrier}. vmcnt(4) only at
// phases 4/8 (certifies next tile; 2 stage-units stay in flight).
// Stage units: A-unit u = row granules {u*64..+64, 128+u*64..+64} (consumed
// by quadrant mh=u in phases 2u+1/2u+2); B-unit v = rows {v*32+k*64..+32}
// (consumed by nh=v in phases v+1/v+3). Write-after-read: each unit's target
// granules are read only in phases >= 1 barrier before its issue; reads of a
// unit occur only after its certifying vmcnt. Accumulation order identical
// to mfma_gemm (bit-identical output).
// ---------------------------------------------------------------------------
template<typename OutT, bool RELU>
__global__ __launch_bounds__(512, 1)
void gemm256_8ph(const bf16* __restrict__ A, const bf16* __restrict__ Bt,
                 const float* __restrict__ bias, OutT* __restrict__ C,
                 int M, int N, int K)
{
    __shared__ bf16 As[2][256 * 64];
    __shared__ bf16 Bs[2][256 * 64];
    const int t = threadIdx.x;          // 0..511
    const int lane = t & 63;
    const int w = t >> 6;               // 0..7
    const int wm = w >> 2, wn = w & 3;  // 2 x 4
    const int m0 = blockIdx.y * 256, n0 = blockIdx.x * 256;
    const int fr = lane & 15;
    const int fq = lane >> 4;
    const int NT = K >> 6;              // even for all our K

#define STAGE_A8(T, U) do {                                                    \
        const int k0_ = (T) * 64;                                              \
        _Pragma("unroll")                                                      \
        for (int i_ = 0; i_ < 2; ++i_) {                                       \
            const int p_ = i_ * 512 + t;                                       \
            const int rl_ = p_ >> 3;                                           \
            const int row_ = ((rl_ >> 6) << 7) + (U) * 64 + (rl_ & 63);        \
            const int c_ = (p_ & 7) ^ (row_ & 7);                              \
            const bf16* g_ = &A[(size_t)(m0 + row_) * K + k0_ + c_ * 8];       \
            __builtin_amdgcn_global_load_lds(                                  \
                (const __attribute__((address_space(1))) unsigned int*)g_,     \
                (__attribute__((address_space(3))) unsigned int*)              \
                    &As[(T) & 1][row_ * 64 + (p_ & 7) * 8], 16, 0, 0);         \
        }                                                                      \
    } while (0)

#define STAGE_B8(T, V) do {                                                    \
        const int k0_ = (T) * 64;                                              \
        _Pragma("unroll")                                                      \
        for (int i_ = 0; i_ < 2; ++i_) {                                       \
            const int p_ = i_ * 512 + t;                                       \
            const int rl_ = p_ >> 3;                                           \
            const int row_ = (V) * 32 + ((rl_ >> 5) << 6) + (rl_ & 31);        \
            const int c_ = (p_ & 7) ^ (row_ & 7);                              \
            const bf16* g_ = &Bt[(size_t)(n0 + row_) * K + k0_ + c_ * 8];      \
            __builtin_amdgcn_global_load_lds(                                  \
                (const __attribute__((address_space(1))) unsigned int*)g_,     \
                (__attribute__((address_space(3))) unsigned int*)              \
                    &Bs[(T) & 1][row_ * 64 + (p_ & 7) * 8], 16, 0, 0);         \
        }                                                                      \
    } while (0)

#define PHASE8(DB, MH, NH, STAGE_STMT, VM_STMT) do {                           \
        short8 af_[4][2], bf_[2][2];                                           \
        _Pragma("unroll")                                                      \
        for (int m2 = 0; m2 < 4; ++m2) {                                       \
            const int row = wm * 128 + (MH) * 64 + m2 * 16 + fr;               \
            _Pragma("unroll")                                                  \
            for (int ks = 0; ks < 2; ++ks) {                                   \
                const int slot = (ks * 4 + fq) ^ (row & 7);                    \
                af_[m2][ks] = *(const short8*)&As[DB][row * 64 + slot * 8];    \
            }                                                                  \
        }                                                                      \
        _Pragma("unroll")                                                      \
        for (int n2 = 0; n2 < 2; ++n2) {                                       \
            const int row = wn * 64 + (NH) * 32 + n2 * 16 + fr;                \
            _Pragma("unroll")                                                  \
            for (int ks = 0; ks < 2; ++ks) {                                   \
                const int slot = (ks * 4 + fq) ^ (row & 7);                    \
                bf_[n2][ks] = *(const short8*)&Bs[DB][row * 64 + slot * 8];    \
            }                                                                  \
        }                                                                      \
        STAGE_STMT;                                                            \
        __builtin_amdgcn_s_barrier();                                          \
        asm volatile("s_waitcnt lgkmcnt(0)" ::: "memory");                     \
        __builtin_amdgcn_sched_barrier(0);                                     \
        __builtin_amdgcn_s_setprio(1);                                         \
        _Pragma("unroll")                                                      \
        for (int m2 = 0; m2 < 4; ++m2)                                         \
            _Pragma("unroll")                                                  \
            for (int n2 = 0; n2 < 2; ++n2) {                                   \
                acc[(MH) * 4 + m2][(NH) * 2 + n2] =                            \
                    __builtin_amdgcn_mfma_f32_16x16x32_bf16(                   \
                        af_[m2][0], bf_[n2][0],                                \
                        acc[(MH) * 4 + m2][(NH) * 2 + n2], 0, 0, 0);           \
                acc[(MH) * 4 + m2][(NH) * 2 + n2] =                            \
                    __builtin_amdgcn_mfma_f32_16x16x32_bf16(                   \
                        af_[m2][1], bf_[n2][1],                                \
                        acc[(MH) * 4 + m2][(NH) * 2 + n2], 0, 0, 0);           \
            }                                                                  \
        __builtin_amdgcn_s_setprio(0);                                         \
        VM_STMT;                                                               \
        __builtin_amdgcn_s_barrier();                                          \
    } while (0)

    f32x4 acc[8][4];
    #pragma unroll
    for (int i = 0; i < 8; ++i)
        #pragma unroll
        for (int j = 0; j < 4; ++j)
            acc[i][j] = (f32x4){0.f, 0.f, 0.f, 0.f};

    // prologue: T0 fully (8 loads) + T1 units Au0,Bu0 (4 loads)
    STAGE_A8(0, 0); STAGE_A8(0, 1); STAGE_B8(0, 0); STAGE_B8(0, 1);
    STAGE_A8(1, 0); STAGE_B8(1, 0);
    asm volatile("s_waitcnt vmcnt(4)" ::: "memory");   // certify T0
    __builtin_amdgcn_s_barrier();

    for (int it = 0; it < (NT >> 1); ++it) {
        const int T0 = 2 * it;
        const bool more = (T0 + 2 < NT);   // NT even => also T0+3 < NT
        // phases 1-4: compute T0 (buf0)
        PHASE8(0, 0, 0, STAGE_A8(T0 + 1, 1), (void)0);
        PHASE8(0, 0, 1, STAGE_B8(T0 + 1, 1), (void)0);
        PHASE8(0, 1, 0, if (more) STAGE_A8(T0 + 2, 0), (void)0);
        PHASE8(0, 1, 1, if (more) STAGE_B8(T0 + 2, 0),
               if (more) { asm volatile("s_waitcnt vmcnt(4)" ::: "memory"); }
               else      { asm volatile("s_waitcnt vmcnt(0)" ::: "memory"); });
        // phases 5-8: compute T1 (buf1)
        PHASE8(1, 0, 0, if (more) STAGE_A8(T0 + 2, 1), (void)0);
        PHASE8(1, 0, 1, if (more) STAGE_B8(T0 + 2, 1), (void)0);
        PHASE8(1, 1, 0, if (more) STAGE_A8(T0 + 3, 0), (void)0);
        PHASE8(1, 1, 1, if (more) STAGE_B8(T0 + 3, 0),
               if (more) { asm volatile("s_waitcnt vmcnt(4)" ::: "memory"); });
    }
#undef PHASE8
#undef STAGE_A8
#undef STAGE_B8

    // epilogue
    #pragma unroll
    for (int ni = 0; ni < 4; ++ni) {
        const int cn = n0 + wn * 64 + ni * 16 + fr;
        const float bv = bias[cn];
        #pragma unroll
        for (int mi = 0; mi < 8; ++mi) {
            const int rbase = m0 + wm * 128 + mi * 16 + fq * 4;
            #pragma unroll
            for (int j = 0; j < 4; ++j) {
                float v = acc[mi][ni][j] + bv;
                if (RELU) v = fmaxf(v, 0.f);
                store_val(&C[(size_t)(rbase + j) * N + cn], v);
            }
        }
    }
}

// ---------------------------------------------------------------------------
// Fused q+v projection: grid.z selects {WqT,bq -> qbf (row-major)} (z=0) or
// {WvT,bv -> vt [B*H,64,S] transposed} (z=1).
// ---------------------------------------------------------------------------
__global__ __launch_bounds__(256, 2)
void mfma_gemm_qv(const bf16* __restrict__ A,
                  const bf16* __restrict__ Bq, const bf16* __restrict__ Bv,
                  const float* __restrict__ biasq, const float* __restrict__ biasv,
                  bf16* __restrict__ Cq, bf16* __restrict__ Cv)
{
    const int M = BSROWS, N = HD, K = EE;
    const bool isv = (blockIdx.z == 1);
    const bf16* Bt = isv ? Bv : Bq;
    const float* bias = isv ? biasv : biasq;

    __shared__ bf16 As[128 * 64];
    __shared__ bf16 Bs[128 * 64];
    const int t = threadIdx.x;
    const int lane = t & 63;
    const int w = t >> 6;
    const int wm = w >> 1, wn = w & 1;
    const int m0 = blockIdx.y * 128, n0 = blockIdx.x * 128;
    const int fr = lane & 15;
    const int fq = lane >> 4;

    f32x4 acc[4][4];
    #pragma unroll
    for (int i = 0; i < 4; ++i)
        #pragma unroll
        for (int j = 0; j < 4; ++j)
            acc[i][j] = (f32x4){0.f, 0.f, 0.f, 0.f};

    for (int k0 = 0; k0 < K; k0 += 64) {
        asm volatile("s_waitcnt lgkmcnt(0)" ::: "memory");
        __syncthreads();
        #pragma unroll
        for (int i = 0; i < 4; ++i) {
            const int p = (w * 4 + i) * 64 + lane;
            const int m = p >> 3;
            const int c = (p & 7) ^ (m & 7);
            const bf16* ga = &A [(size_t)(m0 + m) * K + k0 + c * 8];
            const bf16* gb = &Bt[(size_t)(n0 + m) * K + k0 + c * 8];
            bf16* la = &As[(size_t)(w * 4 + i) * 512];
            bf16* lb = &Bs[(size_t)(w * 4 + i) * 512];
            __builtin_amdgcn_global_load_lds(
                (const __attribute__((address_space(1))) unsigned int*)ga,
                (__attribute__((address_space(3))) unsigned int*)la, 16, 0, 0);
            __builtin_amdgcn_global_load_lds(
                (const __attribute__((address_space(1))) unsigned int*)gb,
                (__attribute__((address_space(3))) unsigned int*)lb, 16, 0, 0);
        }
        asm volatile("s_waitcnt vmcnt(0)" ::: "memory");
        __syncthreads();

        short8 af[4][2], bfr[4][2];
        #pragma unroll
        for (int mi = 0; mi < 4; ++mi) {
            const int row = wm * 64 + mi * 16 + fr;
            #pragma unroll
            for (int kh = 0; kh < 2; ++kh) {
                const int slot = (kh * 4 + fq) ^ (row & 7);
                af[mi][kh] = *(const short8*)&As[row * 64 + slot * 8];
            }
        }
        #pragma unroll
        for (int ni = 0; ni < 4; ++ni) {
            const int row = wn * 64 + ni * 16 + fr;
            #pragma unroll
            for (int kh = 0; kh < 2; ++kh) {
                const int slot = (kh * 4 + fq) ^ (row & 7);
                bfr[ni][kh] = *(const short8*)&Bs[row * 64 + slot * 8];
            }
        }
        #pragma unroll
        for (int mi = 0; mi < 4; ++mi)
            #pragma unroll
            for (int ni = 0; ni < 4; ++ni) {
                acc[mi][ni] = __builtin_amdgcn_mfma_f32_16x16x32_bf16(
                    af[mi][0], bfr[ni][0], acc[mi][ni], 0, 0, 0);
                acc[mi][ni] = __builtin_amdgcn_mfma_f32_16x16x32_bf16(
                    af[mi][1], bfr[ni][1], acc[mi][ni], 0, 0, 0);
            }
    }

    #pragma unroll
    for (int ni = 0; ni < 4; ++ni) {
        const int cn = n0 + wn * 64 + ni * 16 + fr;
        const float bv = bias[cn];
        #pragma unroll
        for (int mi = 0; mi < 4; ++mi) {
            const int rbase = m0 + wm * 64 + mi * 16 + fq * 4;
            if (isv) {
                const int bidx = rbase >> 11, sidx = rbase & (SS - 1);
                const int hh = cn >> 6, dd = cn & 63;
                alignas(8) bf16 tmp[4];
                #pragma unroll
                for (int j = 0; j < 4; ++j)
                    tmp[j] = __float2bfloat16(acc[mi][ni][j] + bv);
                *(ushort4*)(Cv + (((size_t)(bidx * HH + hh) * 64 + dd) * SS + sidx))
                    = *(const ushort4*)tmp;
            } else {
                #pragma unroll
                for (int j = 0; j < 4; ++j)
                    Cq[(size_t)(rbase + j) * N + cn]
                        = __float2bfloat16(acc[mi][ni][j] + bv);
            }
        }
    }
}

// ---------------------------------------------------------------------------
// MFMA flash attention (single-buffered, Q via LDS, KVBLK=64, l via ones-MFMA).
// q layout [B*S, HD] bf16 (k = q, source bug); vt [B*H, 64(d), S] bf16.
// Causal + input_mask cols; all-masked row -> diagonal p=1 at final tile
// (=> out = v[row], matches reference).
// ---------------------------------------------------------------------------
__global__ __launch_bounds__(256, 2)
void attn_mfma(const bf16* __restrict__ qg, const bf16* __restrict__ vtg,
               const int* __restrict__ maskg, bf16* __restrict__ outg)
{
    const int qt = (int)(gridDim.x - 1 - blockIdx.x);   // 31..0 (big tiles first)
    const int h  = blockIdx.y;
    const int b  = blockIdx.z;
    __shared__ bf16 Ks[64 * 64];   // XOR-swizzled K rows (= q rows)
    __shared__ bf16 Vts[64 * 64];  // XOR-swizzled Vt rows [d][kv]
    __shared__ bf16 Ps[64][72];    // P row-major [q][kv] (wave-local rows)
    const int t = threadIdx.x;
    const int lane = t & 63;
    const int w = t >> 6;
    const int fr = lane & 15;
    const int g  = lane >> 4;
    const int q0 = qt * 64;

    // ---- stage own Q tile into Ks, extract A-frags to registers ----
    #pragma unroll
    for (int i = 0; i < 2; ++i) {
        const int pc = i * 256 + t;
        const int m = pc >> 3, c = (pc & 7) ^ (m & 7);
        const bf16* src = qg + ((size_t)(b * SS + q0 + m) * HD + h * 64 + c * 8);
        __builtin_amdgcn_global_load_lds(
            (const __attribute__((address_space(1))) unsigned int*)src,
            (__attribute__((address_space(3))) unsigned int*)&Ks[pc * 8], 16, 0, 0);
    }
    asm volatile("s_waitcnt vmcnt(0)" ::: "memory");
    __syncthreads();
    short8 qa[2];
    {
        const int row = w * 16 + fr;
        #pragma unroll
        for (int s = 0; s < 2; ++s) {
            const int slot = (s * 4 + g) ^ (row & 7);
            qa[s] = *(const short8*)&Ks[row * 64 + slot * 8];
        }
    }
    // ones operand for the l-sum MFMA (bf16 1.0 = 0x3F80)
    short8 ones;
    #pragma unroll
    for (int i = 0; i < 8; ++i) ones[i] = (short)0x3F80;

    f32x4 o_acc[4];
    #pragma unroll
    for (int i = 0; i < 4; ++i) o_acc[i] = (f32x4){0.f, 0.f, 0.f, 0.f};
    f32x4 acc_l = (f32x4){0.f, 0.f, 0.f, 0.f};   // reg j = l for q-row g*4+j
    float run_m[4];
    #pragma unroll
    for (int j = 0; j < 4; ++j) run_m[j] = -INFINITY;

    for (int kvt = 0; kvt <= qt; ++kvt) {
        const int kv0 = kvt * 64;
        asm volatile("s_waitcnt lgkmcnt(0)" ::: "memory");
        __syncthreads();   // all waves done reading Ks/Vts (and qa pre-loop)
        #pragma unroll
        for (int i = 0; i < 2; ++i) {
            const int pc = i * 256 + t;
            const int m = pc >> 3, c = (pc & 7) ^ (m & 7);
            const bf16* ksrc = qg  + ((size_t)(b * SS + kv0 + m) * HD + h * 64 + c * 8);
            const bf16* vsrc = vtg + (((size_t)(b * HH + h) * 64 + m) * SS + kv0 + c * 8);
            __builtin_amdgcn_global_load_lds(
                (const __attribute__((address_space(1))) unsigned int*)ksrc,
                (__attribute__((address_space(3))) unsigned int*)&Ks[pc * 8], 16, 0, 0);
            __builtin_amdgcn_global_load_lds(
                (const __attribute__((address_space(1))) unsigned int*)vsrc,
                (__attribute__((address_space(3))) unsigned int*)&Vts[pc * 8], 16, 0, 0);
        }
        // per-lane mask loads, overlapped with the staging DMA
        int mv[4];
        #pragma unroll
        for (int ni = 0; ni < 4; ++ni)
            mv[ni] = maskg[b * SS + kv0 + ni * 16 + fr];
        asm volatile("s_waitcnt vmcnt(0)" ::: "memory");
        __syncthreads();

        // ---- QK^T: S[q, kv] ----
        f32x4 acc_s[4];
        #pragma unroll
        for (int ni = 0; ni < 4; ++ni) acc_s[ni] = (f32x4){0.f, 0.f, 0.f, 0.f};
        __builtin_amdgcn_s_setprio(1);
        #pragma unroll
        for (int ni = 0; ni < 4; ++ni) {
            const int row = ni * 16 + fr;
            #pragma unroll
            for (int s = 0; s < 2; ++s) {
                const int slot = (s * 4 + g) ^ (row & 7);
                short8 kb = *(const short8*)&Ks[row * 64 + slot * 8];
                acc_s[ni] = __builtin_amdgcn_mfma_f32_16x16x32_bf16(
                    qa[s], kb, acc_s[ni], 0, 0, 0);
            }
        }
        __builtin_amdgcn_s_setprio(0);

        // ---- masked online softmax (rows = g*4+j, cols = ni*16+fr) ----
        float sv[4][4], mj[4], alpha[4];
        #pragma unroll
        for (int j = 0; j < 4; ++j) mj[j] = -INFINITY;
        #pragma unroll
        for (int ni = 0; ni < 4; ++ni) {
            const int kvcol = kv0 + ni * 16 + fr;
            const bool mok = (mv[ni] != 0);
            #pragma unroll
            for (int j = 0; j < 4; ++j) {
                const int qrow = q0 + w * 16 + g * 4 + j;
                const bool valid = mok && (kvcol <= qrow);
                const float s = valid ? acc_s[ni][j] * 0.125f : -INFINITY;
                sv[ni][j] = s;
                mj[j] = fmaxf(mj[j], s);
            }
        }
        #pragma unroll
        for (int j = 0; j < 4; ++j) {
            #pragma unroll
            for (int off = 1; off < 16; off <<= 1)
                mj[j] = fmaxf(mj[j], __shfl_xor(mj[j], off));
            const float newm = fmaxf(run_m[j], mj[j]);
            const float al = (newm == -INFINITY) ? 1.f : __expf(run_m[j] - newm);
            #pragma unroll
            for (int ni = 0; ni < 4; ++ni) {
                float pv = (sv[ni][j] == -INFINITY) ? 0.f : __expf(sv[ni][j] - newm);
                if (kvt == qt && newm == -INFINITY) {
                    const int dloc = w * 16 + g * 4 + j;   // diag: kv==qrow
                    if ((dloc >> 4) == ni && (dloc & 15) == fr) pv = 1.f;
                }
                sv[ni][j] = pv;
            }
            run_m[j] = newm;
            alpha[j] = al;
        }
        // write P (bf16) to wave-local LDS rows; rescale o and l
        #pragma unroll
        for (int ni = 0; ni < 4; ++ni)
            #pragma unroll
            for (int j = 0; j < 4; ++j)
                Ps[w * 16 + g * 4 + j][ni * 16 + fr] = __float2bfloat16(sv[ni][j]);
        #pragma unroll
        for (int nt = 0; nt < 4; ++nt)
            #pragma unroll
            for (int j = 0; j < 4; ++j)
                o_acc[nt][j] *= alpha[j];
        #pragma unroll
        for (int j = 0; j < 4; ++j) acc_l[j] *= alpha[j];

        // ---- PV: o[q, d] += P[q, kv] @ Vt[d, kv]^T; l += P @ 1s ----
        short8 pa[2];
        #pragma unroll
        for (int s = 0; s < 2; ++s)
            pa[s] = *(const short8*)&Ps[w * 16 + fr][s * 32 + g * 8];
        __builtin_amdgcn_s_setprio(1);
        #pragma unroll
        for (int nt = 0; nt < 4; ++nt) {
            const int row = nt * 16 + fr;
            #pragma unroll
            for (int s = 0; s < 2; ++s) {
                const int slot = (s * 4 + g) ^ (row & 7);
                short8 vb = *(const short8*)&Vts[row * 64 + slot * 8];
                o_acc[nt] = __builtin_amdgcn_mfma_f32_16x16x32_bf16(
                    pa[s], vb, o_acc[nt], 0, 0, 0);
            }
        }
        #pragma unroll
        for (int s = 0; s < 2; ++s)
            acc_l = __builtin_amdgcn_mfma_f32_16x16x32_bf16(
                pa[s], ones, acc_l, 0, 0, 0);
        __builtin_amdgcn_s_setprio(0);
    }

    // ---- epilogue ----
    float inv[4];
    #pragma unroll
    for (int j = 0; j < 4; ++j) inv[j] = (acc_l[j] > 0.f) ? 1.f / acc_l[j] : 0.f;
    #pragma unroll
    for (int nt = 0; nt < 4; ++nt)
        #pragma unroll
        for (int j = 0; j < 4; ++j)
            outg[(size_t)(b * SS + q0 + w * 16 + g * 4 + j) * HD + h * 64 + nt * 16 + fr]
                = __float2bfloat16(o_acc[nt][j] * inv[j]);
}

// ---------------------------------------------------------------------------
extern "C" void kernel_launch(void* const* d_in, const int* in_sizes, int n_in,
                              void* d_out, int out_size, void* d_ws, size_t ws_size,
                              hipStream_t stream)
{
    const float* x    = (const float*)d_in[0];
    const float* Wq   = (const float*)d_in[1];
    const float* bq   = (const float*)d_in[2];
    const float* Wv   = (const float*)d_in[3];
    const float* bv   = (const float*)d_in[4];
    const float* Wo   = (const float*)d_in[5];
    const float* bo   = (const float*)d_in[6];
    const float* ln1g = (const float*)d_in[7];
    const float* ln1b = (const float*)d_in[8];
    const float* W1   = (const float*)d_in[9];
    const float* b1   = (const float*)d_in[10];
    const float* W2   = (const float*)d_in[11];
    const float* b2   = (const float*)d_in[12];
    const float* W3   = (const float*)d_in[13];
    const float* b3   = (const float*)d_in[14];
    const float* ln2g = (const float*)d_in[15];
    const float* ln2b = (const float*)d_in[16];
    const int*   mask = (const int*)d_in[17];
    float* out = (float*)d_out;
    char* wsb  = (char*)d_ws;

    // workspace (~96.4 MB). Liveness aliasing: h1 (25.2MB) overlays
    // [qbf|vt|attno|pad] (all dead by FF1); xln reused as y1ln.
    size_t off = 0;
    bf16* WqT = (bf16*)(wsb + off); off += (size_t)EE * HD * 2;
    bf16* WvT = (bf16*)(wsb + off); off += (size_t)EE * HD * 2;
    bf16* WoT = (bf16*)(wsb + off); off += (size_t)HD * EE * 2;
    bf16* W1T = (bf16*)(wsb + off); off += (size_t)EE * FF * 2;
    bf16* W3T = (bf16*)(wsb + off); off += (size_t)FF * EE * 2;
    bf16* W2T = (bf16*)(wsb + off); off += (size_t)FF * FF * 2;
    bf16* qbf = (bf16*)(wsb + off);
    bf16* h1  = qbf;                  off += (size_t)BSROWS * HD * 2;
    bf16* vt  = (bf16*)(wsb + off);   off += (size_t)BSROWS * HD * 2;
    bf16* attno = (bf16*)(wsb + off); off += (size_t)BSROWS * HD * 2;
    /* pad for h1 tail */             off += (size_t)BSROWS * HD * 2;
    bf16* xln = (bf16*)(wsb + off);   off += (size_t)BSROWS * EE * 2;
    bf16* h2  = (bf16*)(wsb + off);   off += (size_t)BSROWS * FF * 2;
    float* y1 = (float*)(wsb + off);  off += (size_t)BSROWS * EE * 4;

    // 1. all weight transposes + bf16 convert in one dispatch
    transpose_all<<<15552, 256, 0, stream>>>(Wq, Wv, Wo, W1, W2, W3,
                                             WqT, WvT, WoT, W1T, W2T, W3T);
    // 2. LN1 -> bf16
    ln_kernel<bf16><<<BSROWS, 256, 0, stream>>>(x, ln1g, ln1b, xln);
    // 3. fused q+v projection: z=0 -> qbf, z=1 -> vt [B*H, 64, S]
    dim3 gp(HD / 128, BSROWS / 128);
    mfma_gemm_qv<<<dim3(gp.x, gp.y, 2), 256, 0, stream>>>(
        xln, WqT, WvT, bq, bv, qbf, vt);
    // 4. MFMA flash attention -> attno (bf16)
    attn_mfma<<<dim3(SS/64, HH, BB), 256, 0, stream>>>(qbf, vt, mask, attno);
    // 5. O-proj + residual x -> y1 (f32)
    mfma_gemm<float, false, true><<<gp, 256, 0, stream>>>(attno, WoT, bo, x, y1, BSROWS, EE, HD);
    // 6. LN2: y1 -> y1ln (reuse xln)
    bf16* y1ln = xln;
    ln_kernel<bf16><<<BSROWS, 256, 0, stream>>>(y1, ln2g, ln2b, y1ln);
    // 7. FF1: h1 = relu(y1ln @ W1 + b1)   [8-phase 256x256 GEMM]
    dim3 g256(FF / 256, BSROWS / 256);
    gemm256_8ph<bf16, true><<<g256, 512, 0, stream>>>(y1ln, W1T, b1, h1, BSROWS, FF, EE);
    // 8. FF2: h2 = relu(h1 @ W2 + b2)     [8-phase 256x256 GEMM]
    gemm256_8ph<bf16, true><<<g256, 512, 0, stream>>>(h1, W2T, b2, h2, BSROWS, FF, FF);
    // 9. FF3: out = h2 @ W3 + b3 + y1
    mfma_gemm<float, false, true><<<gp, 256, 0, stream>>>(h2, W3T, b3, y1, out, BSROWS, EE, FF);
}

// Round 14
// 300.255 us; speedup vs baseline: 1.1419x; 1.1419x over previous
//
#include <hip/hip_runtime.h>
#include <hip/hip_bf16.h>
#include <math.h>

// Problem constants
#define BB 2
#define SS 2048
#define EE 768
#define HH 12
#define DD 64
#define FF 3072
#define BSROWS (BB*SS)      // 4096
#define HD (HH*DD)          // 768

typedef __hip_bfloat16 bf16;
typedef __attribute__((ext_vector_type(8))) short short8;
typedef __attribute__((ext_vector_type(4))) float f32x4;

__device__ inline void store_val(float* p, float v) { *p = v; }
__device__ inline void store_val(bf16* p, float v)  { *p = __float2bfloat16(v); }

// ---------------------------------------------------------------------------
// All 6 weight transposes (f32 -> bf16, [R,C] -> [C,R] per z-slice) in ONE
// kernel. 32x32 tiles; blockIdx.x decoded against compile-time tile ranges.
// ---------------------------------------------------------------------------
__global__ __launch_bounds__(256)
void transpose_all(const float* __restrict__ Wq, const float* __restrict__ Wv,
                   const float* __restrict__ Wo, const float* __restrict__ W1,
                   const float* __restrict__ W2, const float* __restrict__ W3,
                   bf16* __restrict__ WqT, bf16* __restrict__ WvT,
                   bf16* __restrict__ WoT, bf16* __restrict__ W1T,
                   bf16* __restrict__ W2T, bf16* __restrict__ W3T)
{
    const int id = blockIdx.x;
    const float* in; bf16* out; int R, C, z = 0, local;
    if (id < 1152) {                       // Wq / Wv: 12 slices of [768, 64]
        const bool isv = id >= 576;
        local = isv ? id - 576 : id;
        in = isv ? Wv : Wq; out = isv ? WvT : WqT;
        R = EE; C = DD;
        z = local / 48; local -= z * 48;
    } else if (id < 1728)  { in = Wo; out = WoT; R = HD; C = EE; local = id - 1152; }
    else if (id < 4032)    { in = W1; out = W1T; R = EE; C = FF; local = id - 1728; }
    else if (id < 13248)   { in = W2; out = W2T; R = FF; C = FF; local = id - 4032; }
    else                   { in = W3; out = W3T; R = FF; C = EE; local = id - 13248; }
    const int tiles_x = C >> 5;
    const int ty = local / tiles_x, tx = local - ty * tiles_x;
    const int r0 = ty * 32, c0 = tx * 32;
    const size_t zoff = (size_t)z * R * C;

    __shared__ float tile[32][33];
    const int t = threadIdx.x;
    const int lr = t >> 5, lc = t & 31;
    #pragma unroll
    for (int i = 0; i < 4; ++i)
        tile[lr + 8 * i][lc] = in[zoff + (size_t)(r0 + lr + 8 * i) * C + c0 + lc];
    __syncthreads();
    #pragma unroll
    for (int i = 0; i < 4; ++i)
        out[zoff + (size_t)(c0 + lr + 8 * i) * R + r0 + lc] =
            __float2bfloat16(tile[lc][lr + 8 * i]);
}

// ---------------------------------------------------------------------------
// LayerNorm: one block (256 thr) per row of 768; f32 in, OutT out
// ---------------------------------------------------------------------------
template<typename OutT>
__global__ __launch_bounds__(256)
void ln_kernel(const float* __restrict__ x, const float* __restrict__ g,
               const float* __restrict__ bt, OutT* __restrict__ o)
{
    const int row = blockIdx.x;
    const float* xr = x + (size_t)row * EE;
    const int t = threadIdx.x;
    float v0 = xr[t], v1 = xr[t + 256], v2 = xr[t + 512];
    float s = v0 + v1 + v2;
    #pragma unroll
    for (int off = 32; off > 0; off >>= 1) s += __shfl_xor(s, off);
    __shared__ float red[8];
    const int w = t >> 6;
    if ((t & 63) == 0) red[w] = s;
    __syncthreads();
    const float mean = (red[0] + red[1] + red[2] + red[3]) * (1.f / 768.f);
    float d0 = v0 - mean, d1 = v1 - mean, d2 = v2 - mean;
    float q = d0 * d0 + d1 * d1 + d2 * d2;
    #pragma unroll
    for (int off = 32; off > 0; off >>= 1) q += __shfl_xor(q, off);
    if ((t & 63) == 0) red[4 + w] = q;
    __syncthreads();
    const float var = (red[4] + red[5] + red[6] + red[7]) * (1.f / 768.f);
    const float rstd = rsqrtf(var + 1e-5f);
    OutT* orow = o + (size_t)row * EE;
    store_val(&orow[t],       d0 * rstd * g[t]       + bt[t]);
    store_val(&orow[t + 256], d1 * rstd * g[t + 256] + bt[t + 256]);
    store_val(&orow[t + 512], d2 * rstd * g[t + 512] + bt[t + 512]);
}

// ---------------------------------------------------------------------------
// bf16 MFMA GEMM (m97 structure): C[M,N] = A[M,K] @ Bt[N,K]^T + bias (+res)
// 128x128 tile, BK=64, 4 waves (2x2). XOR swizzle slot = c ^ (row&7) applied
// on the pre-swizzled GLOBAL source (LDS dest linear); read applies same XOR.
// VT: write C transposed per-head as vt[B*H, 64(d), S] (for attention V^T).
// ---------------------------------------------------------------------------
template<typename OutT, bool RELU, bool HAS_RES, bool VT = false>
__global__ __launch_bounds__(256, 2)
void mfma_gemm(const bf16* __restrict__ A, const bf16* __restrict__ Bt,
               const float* __restrict__ bias, const float* __restrict__ res,
               OutT* __restrict__ C, int M, int N, int K)
{
    __shared__ bf16 As[128 * 64];
    __shared__ bf16 Bs[128 * 64];
    const int t = threadIdx.x;
    const int lane = t & 63;
    const int w = t >> 6;
    const int wm = w >> 1, wn = w & 1;
    const int m0 = blockIdx.y * 128, n0 = blockIdx.x * 128;
    const int fr = lane & 15;
    const int fq = lane >> 4;

    f32x4 acc[4][4];
    #pragma unroll
    for (int i = 0; i < 4; ++i)
        #pragma unroll
        for (int j = 0; j < 4; ++j)
            acc[i][j] = (f32x4){0.f, 0.f, 0.f, 0.f};

    for (int k0 = 0; k0 < K; k0 += 64) {
        asm volatile("s_waitcnt lgkmcnt(0)" ::: "memory");
        __syncthreads();
        #pragma unroll
        for (int i = 0; i < 4; ++i) {
            const int p = (w * 4 + i) * 64 + lane;
            const int m = p >> 3;
            const int c = (p & 7) ^ (m & 7);
            const bf16* ga = &A [(size_t)(m0 + m) * K + k0 + c * 8];
            const bf16* gb = &Bt[(size_t)(n0 + m) * K + k0 + c * 8];
            bf16* la = &As[(size_t)(w * 4 + i) * 512];
            bf16* lb = &Bs[(size_t)(w * 4 + i) * 512];
            __builtin_amdgcn_global_load_lds(
                (const __attribute__((address_space(1))) unsigned int*)ga,
                (__attribute__((address_space(3))) unsigned int*)la, 16, 0, 0);
            __builtin_amdgcn_global_load_lds(
                (const __attribute__((address_space(1))) unsigned int*)gb,
                (__attribute__((address_space(3))) unsigned int*)lb, 16, 0, 0);
        }
        asm volatile("s_waitcnt vmcnt(0)" ::: "memory");
        __syncthreads();

        short8 af[4][2], bfr[4][2];
        #pragma unroll
        for (int mi = 0; mi < 4; ++mi) {
            const int row = wm * 64 + mi * 16 + fr;
            #pragma unroll
            for (int kh = 0; kh < 2; ++kh) {
                const int slot = (kh * 4 + fq) ^ (row & 7);
                af[mi][kh] = *(const short8*)&As[row * 64 + slot * 8];
            }
        }
        #pragma unroll
        for (int ni = 0; ni < 4; ++ni) {
            const int row = wn * 64 + ni * 16 + fr;
            #pragma unroll
            for (int kh = 0; kh < 2; ++kh) {
                const int slot = (kh * 4 + fq) ^ (row & 7);
                bfr[ni][kh] = *(const short8*)&Bs[row * 64 + slot * 8];
            }
        }
        #pragma unroll
        for (int mi = 0; mi < 4; ++mi)
            #pragma unroll
            for (int ni = 0; ni < 4; ++ni) {
                acc[mi][ni] = __builtin_amdgcn_mfma_f32_16x16x32_bf16(
                    af[mi][0], bfr[ni][0], acc[mi][ni], 0, 0, 0);
                acc[mi][ni] = __builtin_amdgcn_mfma_f32_16x16x32_bf16(
                    af[mi][1], bfr[ni][1], acc[mi][ni], 0, 0, 0);
            }
    }

    // epilogue: C/D layout col=lane&15, row=(lane>>4)*4+reg  [m89/m91]
    #pragma unroll
    for (int ni = 0; ni < 4; ++ni) {
        const int cn = n0 + wn * 64 + ni * 16 + fr;
        const float bv = bias[cn];
        #pragma unroll
        for (int mi = 0; mi < 4; ++mi) {
            const int rbase = m0 + wm * 64 + mi * 16 + fq * 4;
            if (VT) {
                const int bidx = rbase >> 11, sidx = rbase & (SS - 1);
                const int hh = cn >> 6, dd = cn & 63;
                alignas(8) bf16 tmp[4];
                #pragma unroll
                for (int j = 0; j < 4; ++j)
                    tmp[j] = __float2bfloat16(acc[mi][ni][j] + bv);
                *(ushort4*)((bf16*)C + (((size_t)(bidx * HH + hh) * 64 + dd) * SS + sidx))
                    = *(const ushort4*)tmp;
            } else {
                #pragma unroll
                for (int j = 0; j < 4; ++j) {
                    float v = acc[mi][ni][j] + bv;
                    if (HAS_RES) v += res[(size_t)(rbase + j) * N + cn];
                    if (RELU) v = fmaxf(v, 0.f);
                    store_val(&C[(size_t)(rbase + j) * N + cn], v);
                }
            }
        }
    }
}

// ---------------------------------------------------------------------------
// Fused q+v projection: grid.z selects {WqT,bq -> qbf (row-major)} (z=0) or
// {WvT,bv -> vt [B*H,64,S] transposed} (z=1).
// ---------------------------------------------------------------------------
__global__ __launch_bounds__(256, 2)
void mfma_gemm_qv(const bf16* __restrict__ A,
                  const bf16* __restrict__ Bq, const bf16* __restrict__ Bv,
                  const float* __restrict__ biasq, const float* __restrict__ biasv,
                  bf16* __restrict__ Cq, bf16* __restrict__ Cv)
{
    const int M = BSROWS, N = HD, K = EE;
    const bool isv = (blockIdx.z == 1);
    const bf16* Bt = isv ? Bv : Bq;
    const float* bias = isv ? biasv : biasq;

    __shared__ bf16 As[128 * 64];
    __shared__ bf16 Bs[128 * 64];
    const int t = threadIdx.x;
    const int lane = t & 63;
    const int w = t >> 6;
    const int wm = w >> 1, wn = w & 1;
    const int m0 = blockIdx.y * 128, n0 = blockIdx.x * 128;
    const int fr = lane & 15;
    const int fq = lane >> 4;

    f32x4 acc[4][4];
    #pragma unroll
    for (int i = 0; i < 4; ++i)
        #pragma unroll
        for (int j = 0; j < 4; ++j)
            acc[i][j] = (f32x4){0.f, 0.f, 0.f, 0.f};

    for (int k0 = 0; k0 < K; k0 += 64) {
        asm volatile("s_waitcnt lgkmcnt(0)" ::: "memory");
        __syncthreads();
        #pragma unroll
        for (int i = 0; i < 4; ++i) {
            const int p = (w * 4 + i) * 64 + lane;
            const int m = p >> 3;
            const int c = (p & 7) ^ (m & 7);
            const bf16* ga = &A [(size_t)(m0 + m) * K + k0 + c * 8];
            const bf16* gb = &Bt[(size_t)(n0 + m) * K + k0 + c * 8];
            bf16* la = &As[(size_t)(w * 4 + i) * 512];
            bf16* lb = &Bs[(size_t)(w * 4 + i) * 512];
            __builtin_amdgcn_global_load_lds(
                (const __attribute__((address_space(1))) unsigned int*)ga,
                (__attribute__((address_space(3))) unsigned int*)la, 16, 0, 0);
            __builtin_amdgcn_global_load_lds(
                (const __attribute__((address_space(1))) unsigned int*)gb,
                (__attribute__((address_space(3))) unsigned int*)lb, 16, 0, 0);
        }
        asm volatile("s_waitcnt vmcnt(0)" ::: "memory");
        __syncthreads();

        short8 af[4][2], bfr[4][2];
        #pragma unroll
        for (int mi = 0; mi < 4; ++mi) {
            const int row = wm * 64 + mi * 16 + fr;
            #pragma unroll
            for (int kh = 0; kh < 2; ++kh) {
                const int slot = (kh * 4 + fq) ^ (row & 7);
                af[mi][kh] = *(const short8*)&As[row * 64 + slot * 8];
            }
        }
        #pragma unroll
        for (int ni = 0; ni < 4; ++ni) {
            const int row = wn * 64 + ni * 16 + fr;
            #pragma unroll
            for (int kh = 0; kh < 2; ++kh) {
                const int slot = (kh * 4 + fq) ^ (row & 7);
                bfr[ni][kh] = *(const short8*)&Bs[row * 64 + slot * 8];
            }
        }
        #pragma unroll
        for (int mi = 0; mi < 4; ++mi)
            #pragma unroll
            for (int ni = 0; ni < 4; ++ni) {
                acc[mi][ni] = __builtin_amdgcn_mfma_f32_16x16x32_bf16(
                    af[mi][0], bfr[ni][0], acc[mi][ni], 0, 0, 0);
                acc[mi][ni] = __builtin_amdgcn_mfma_f32_16x16x32_bf16(
                    af[mi][1], bfr[ni][1], acc[mi][ni], 0, 0, 0);
            }
    }

    #pragma unroll
    for (int ni = 0; ni < 4; ++ni) {
        const int cn = n0 + wn * 64 + ni * 16 + fr;
        const float bv = bias[cn];
        #pragma unroll
        for (int mi = 0; mi < 4; ++mi) {
            const int rbase = m0 + wm * 64 + mi * 16 + fq * 4;
            if (isv) {
                const int bidx = rbase >> 11, sidx = rbase & (SS - 1);
                const int hh = cn >> 6, dd = cn & 63;
                alignas(8) bf16 tmp[4];
                #pragma unroll
                for (int j = 0; j < 4; ++j)
                    tmp[j] = __float2bfloat16(acc[mi][ni][j] + bv);
                *(ushort4*)(Cv + (((size_t)(bidx * HH + hh) * 64 + dd) * SS + sidx))
                    = *(const ushort4*)tmp;
            } else {
                #pragma unroll
                for (int j = 0; j < 4; ++j)
                    Cq[(size_t)(rbase + j) * N + cn]
                        = __float2bfloat16(acc[mi][ni][j] + bv);
            }
        }
    }
}

// ---------------------------------------------------------------------------
// MFMA flash attention, PAIRED-qt load balance. Block pr handles qt=31-pr
// then qt=pr: per-pair work = 33 kv-tiles (constant) -> 384 uniform blocks,
// no tail. Body per qt is the proven single-buffered KVBLK=64 structure with
// l-via-ones-MFMA; per-tile math byte-identical to round 11.
// q layout [B*S, HD] bf16 (k = q, source bug); vt [B*H, 64(d), S] bf16.
// Causal + input_mask cols; all-masked row -> diagonal p=1 at final tile
// (=> out = v[row], matches reference).
// ---------------------------------------------------------------------------
__global__ __launch_bounds__(256, 2)
void attn_mfma(const bf16* __restrict__ qg, const bf16* __restrict__ vtg,
               const int* __restrict__ maskg, bf16* __restrict__ outg)
{
    const int pr = blockIdx.x;   // 0..15
    const int h  = blockIdx.y;
    const int b  = blockIdx.z;
    __shared__ bf16 Ks[64 * 64];   // XOR-swizzled K rows (= q rows)
    __shared__ bf16 Vts[64 * 64];  // XOR-swizzled Vt rows [d][kv]
    __shared__ bf16 Ps[64][72];    // P row-major [q][kv] (wave-local rows)
    const int t = threadIdx.x;
    const int lane = t & 63;
    const int w = t >> 6;
    const int fr = lane & 15;
    const int g  = lane >> 4;

    // ones operand for the l-sum MFMA (bf16 1.0 = 0x3F80)
    short8 ones;
    #pragma unroll
    for (int i = 0; i < 8; ++i) ones[i] = (short)0x3F80;

    for (int half = 0; half < 2; ++half) {
        const int qt = half == 0 ? (31 - pr) : pr;   // big tile first
        const int q0 = qt * 64;

        // guard: previous half's LDS readers must be done before restaging Q
        asm volatile("s_waitcnt lgkmcnt(0)" ::: "memory");
        __syncthreads();

        // ---- stage own Q tile into Ks, extract A-frags to registers ----
        #pragma unroll
        for (int i = 0; i < 2; ++i) {
            const int pc = i * 256 + t;
            const int m = pc >> 3, c = (pc & 7) ^ (m & 7);
            const bf16* src = qg + ((size_t)(b * SS + q0 + m) * HD + h * 64 + c * 8);
            __builtin_amdgcn_global_load_lds(
                (const __attribute__((address_space(1))) unsigned int*)src,
                (__attribute__((address_space(3))) unsigned int*)&Ks[pc * 8], 16, 0, 0);
        }
        asm volatile("s_waitcnt vmcnt(0)" ::: "memory");
        __syncthreads();
        short8 qa[2];
        {
            const int row = w * 16 + fr;
            #pragma unroll
            for (int s = 0; s < 2; ++s) {
                const int slot = (s * 4 + g) ^ (row & 7);
                qa[s] = *(const short8*)&Ks[row * 64 + slot * 8];
            }
        }

        f32x4 o_acc[4];
        #pragma unroll
        for (int i = 0; i < 4; ++i) o_acc[i] = (f32x4){0.f, 0.f, 0.f, 0.f};
        f32x4 acc_l = (f32x4){0.f, 0.f, 0.f, 0.f};
        float run_m[4];
        #pragma unroll
        for (int j = 0; j < 4; ++j) run_m[j] = -INFINITY;

        for (int kvt = 0; kvt <= qt; ++kvt) {
            const int kv0 = kvt * 64;
            asm volatile("s_waitcnt lgkmcnt(0)" ::: "memory");
            __syncthreads();   // all waves done reading Ks/Vts (and qa)
            #pragma unroll
            for (int i = 0; i < 2; ++i) {
                const int pc = i * 256 + t;
                const int m = pc >> 3, c = (pc & 7) ^ (m & 7);
                const bf16* ksrc = qg  + ((size_t)(b * SS + kv0 + m) * HD + h * 64 + c * 8);
                const bf16* vsrc = vtg + (((size_t)(b * HH + h) * 64 + m) * SS + kv0 + c * 8);
                __builtin_amdgcn_global_load_lds(
                    (const __attribute__((address_space(1))) unsigned int*)ksrc,
                    (__attribute__((address_space(3))) unsigned int*)&Ks[pc * 8], 16, 0, 0);
                __builtin_amdgcn_global_load_lds(
                    (const __attribute__((address_space(1))) unsigned int*)vsrc,
                    (__attribute__((address_space(3))) unsigned int*)&Vts[pc * 8], 16, 0, 0);
            }
            // per-lane mask loads, overlapped with the staging DMA
            int mv[4];
            #pragma unroll
            for (int ni = 0; ni < 4; ++ni)
                mv[ni] = maskg[b * SS + kv0 + ni * 16 + fr];
            asm volatile("s_waitcnt vmcnt(0)" ::: "memory");
            __syncthreads();

            // ---- QK^T: S[q, kv] ----
            f32x4 acc_s[4];
            #pragma unroll
            for (int ni = 0; ni < 4; ++ni) acc_s[ni] = (f32x4){0.f, 0.f, 0.f, 0.f};
            __builtin_amdgcn_s_setprio(1);
            #pragma unroll
            for (int ni = 0; ni < 4; ++ni) {
                const int row = ni * 16 + fr;
                #pragma unroll
                for (int s = 0; s < 2; ++s) {
                    const int slot = (s * 4 + g) ^ (row & 7);
                    short8 kb = *(const short8*)&Ks[row * 64 + slot * 8];
                    acc_s[ni] = __builtin_amdgcn_mfma_f32_16x16x32_bf16(
                        qa[s], kb, acc_s[ni], 0, 0, 0);
                }
            }
            __builtin_amdgcn_s_setprio(0);

            // ---- masked online softmax (rows = g*4+j, cols = ni*16+fr) ----
            float sv[4][4], mj[4], alpha[4];
            #pragma unroll
            for (int j = 0; j < 4; ++j) mj[j] = -INFINITY;
            #pragma unroll
            for (int ni = 0; ni < 4; ++ni) {
                const int kvcol = kv0 + ni * 16 + fr;
                const bool mok = (mv[ni] != 0);
                #pragma unroll
                for (int j = 0; j < 4; ++j) {
                    const int qrow = q0 + w * 16 + g * 4 + j;
                    const bool valid = mok && (kvcol <= qrow);
                    const float s = valid ? acc_s[ni][j] * 0.125f : -INFINITY;
                    sv[ni][j] = s;
                    mj[j] = fmaxf(mj[j], s);
                }
            }
            #pragma unroll
            for (int j = 0; j < 4; ++j) {
                #pragma unroll
                for (int off = 1; off < 16; off <<= 1)
                    mj[j] = fmaxf(mj[j], __shfl_xor(mj[j], off));
                const float newm = fmaxf(run_m[j], mj[j]);
                const float al = (newm == -INFINITY) ? 1.f : __expf(run_m[j] - newm);
                #pragma unroll
                for (int ni = 0; ni < 4; ++ni) {
                    float pv = (sv[ni][j] == -INFINITY) ? 0.f : __expf(sv[ni][j] - newm);
                    if (kvt == qt && newm == -INFINITY) {
                        const int dloc = w * 16 + g * 4 + j;   // diag: kv==qrow
                        if ((dloc >> 4) == ni && (dloc & 15) == fr) pv = 1.f;
                    }
                    sv[ni][j] = pv;
                }
                run_m[j] = newm;
                alpha[j] = al;
            }
            // write P (bf16) to wave-local LDS rows; rescale o and l
            #pragma unroll
            for (int ni = 0; ni < 4; ++ni)
                #pragma unroll
                for (int j = 0; j < 4; ++j)
                    Ps[w * 16 + g * 4 + j][ni * 16 + fr] = __float2bfloat16(sv[ni][j]);
            #pragma unroll
            for (int nt = 0; nt < 4; ++nt)
                #pragma unroll
                for (int j = 0; j < 4; ++j)
                    o_acc[nt][j] *= alpha[j];
            #pragma unroll
            for (int j = 0; j < 4; ++j) acc_l[j] *= alpha[j];

            // ---- PV: o[q, d] += P[q, kv] @ Vt[d, kv]^T; l += P @ 1s ----
            short8 pa[2];
            #pragma unroll
            for (int s = 0; s < 2; ++s)
                pa[s] = *(const short8*)&Ps[w * 16 + fr][s * 32 + g * 8];
            __builtin_amdgcn_s_setprio(1);
            #pragma unroll
            for (int nt = 0; nt < 4; ++nt) {
                const int row = nt * 16 + fr;
                #pragma unroll
                for (int s = 0; s < 2; ++s) {
                    const int slot = (s * 4 + g) ^ (row & 7);
                    short8 vb = *(const short8*)&Vts[row * 64 + slot * 8];
                    o_acc[nt] = __builtin_amdgcn_mfma_f32_16x16x32_bf16(
                        pa[s], vb, o_acc[nt], 0, 0, 0);
                }
            }
            #pragma unroll
            for (int s = 0; s < 2; ++s)
                acc_l = __builtin_amdgcn_mfma_f32_16x16x32_bf16(
                    pa[s], ones, acc_l, 0, 0, 0);
            __builtin_amdgcn_s_setprio(0);
        }

        // ---- epilogue for this qt ----
        float inv[4];
        #pragma unroll
        for (int j = 0; j < 4; ++j) inv[j] = (acc_l[j] > 0.f) ? 1.f / acc_l[j] : 0.f;
        #pragma unroll
        for (int nt = 0; nt < 4; ++nt)
            #pragma unroll
            for (int j = 0; j < 4; ++j)
                outg[(size_t)(b * SS + q0 + w * 16 + g * 4 + j) * HD + h * 64 + nt * 16 + fr]
                    = __float2bfloat16(o_acc[nt][j] * inv[j]);
    }
}

// ---------------------------------------------------------------------------
extern "C" void kernel_launch(void* const* d_in, const int* in_sizes, int n_in,
                              void* d_out, int out_size, void* d_ws, size_t ws_size,
                              hipStream_t stream)
{
    const float* x    = (const float*)d_in[0];
    const float* Wq   = (const float*)d_in[1];
    const float* bq   = (const float*)d_in[2];
    const float* Wv   = (const float*)d_in[3];
    const float* bv   = (const float*)d_in[4];
    const float* Wo   = (const float*)d_in[5];
    const float* bo   = (const float*)d_in[6];
    const float* ln1g = (const float*)d_in[7];
    const float* ln1b = (const float*)d_in[8];
    const float* W1   = (const float*)d_in[9];
    const float* b1   = (const float*)d_in[10];
    const float* W2   = (const float*)d_in[11];
    const float* b2   = (const float*)d_in[12];
    const float* W3   = (const float*)d_in[13];
    const float* b3   = (const float*)d_in[14];
    const float* ln2g = (const float*)d_in[15];
    const float* ln2b = (const float*)d_in[16];
    const int*   mask = (const int*)d_in[17];
    float* out = (float*)d_out;
    char* wsb  = (char*)d_ws;

    // workspace (~96.4 MB). Liveness aliasing: h1 (25.2MB) overlays
    // [qbf|vt|attno|pad] (all dead by FF1); xln reused as y1ln.
    size_t off = 0;
    bf16* WqT = (bf16*)(wsb + off); off += (size_t)EE * HD * 2;
    bf16* WvT = (bf16*)(wsb + off); off += (size_t)EE * HD * 2;
    bf16* WoT = (bf16*)(wsb + off); off += (size_t)HD * EE * 2;
    bf16* W1T = (bf16*)(wsb + off); off += (size_t)EE * FF * 2;
    bf16* W3T = (bf16*)(wsb + off); off += (size_t)FF * EE * 2;
    bf16* W2T = (bf16*)(wsb + off); off += (size_t)FF * FF * 2;
    bf16* qbf = (bf16*)(wsb + off);
    bf16* h1  = qbf;                  off += (size_t)BSROWS * HD * 2;
    bf16* vt  = (bf16*)(wsb + off);   off += (size_t)BSROWS * HD * 2;
    bf16* attno = (bf16*)(wsb + off); off += (size_t)BSROWS * HD * 2;
    /* pad for h1 tail */             off += (size_t)BSROWS * HD * 2;
    bf16* xln = (bf16*)(wsb + off);   off += (size_t)BSROWS * EE * 2;
    bf16* h2  = (bf16*)(wsb + off);   off += (size_t)BSROWS * FF * 2;
    float* y1 = (float*)(wsb + off);  off += (size_t)BSROWS * EE * 4;

    // 1. all weight transposes + bf16 convert in one dispatch
    transpose_all<<<15552, 256, 0, stream>>>(Wq, Wv, Wo, W1, W2, W3,
                                             WqT, WvT, WoT, W1T, W2T, W3T);
    // 2. LN1 -> bf16
    ln_kernel<bf16><<<BSROWS, 256, 0, stream>>>(x, ln1g, ln1b, xln);
    // 3. fused q+v projection: z=0 -> qbf, z=1 -> vt [B*H, 64, S]
    dim3 gp(HD / 128, BSROWS / 128);
    mfma_gemm_qv<<<dim3(gp.x, gp.y, 2), 256, 0, stream>>>(
        xln, WqT, WvT, bq, bv, qbf, vt);
    // 4. MFMA flash attention (paired qt) -> attno (bf16)
    attn_mfma<<<dim3(SS/128, HH, BB), 256, 0, stream>>>(qbf, vt, mask, attno);
    // 5. O-proj + residual x -> y1 (f32)
    mfma_gemm<float, false, true><<<gp, 256, 0, stream>>>(attno, WoT, bo, x, y1, BSROWS, EE, HD);
    // 6. LN2: y1 -> y1ln (reuse xln)
    bf16* y1ln = xln;
    ln_kernel<bf16><<<BSROWS, 256, 0, stream>>>(y1, ln2g, ln2b, y1ln);
    // 7. FF1: h1 = relu(y1ln @ W1 + b1)   [m97 128x128 GEMM]
    dim3 gf(FF / 128, BSROWS / 128);
    mfma_gemm<bf16, true, false><<<gf, 256, 0, stream>>>(y1ln, W1T, b1, nullptr, h1, BSROWS, FF, EE);
    // 8. FF2: h2 = relu(h1 @ W2 + b2)     [m97 128x128 GEMM]
    mfma_gemm<bf16, true, false><<<gf, 256, 0, stream>>>(h1, W2T, b2, nullptr, h2, BSROWS, FF, FF);
    // 9. FF3: out = h2 @ W3 + b3 + y1
    mfma_gemm<float, false, true><<<gp, 256, 0, stream>>>(h2, W3T, b3, y1, out, BSROWS, EE, FF);
}

// Round 15
// 275.779 us; speedup vs baseline: 1.2432x; 1.0888x over previous
//
#include <hip/hip_runtime.h>
#include <hip/hip_bf16.h>
#include <math.h>

// Problem constants
#define BB 2
#define SS 2048
#define EE 768
#define HH 12
#define DD 64
#define FF 3072
#define BSROWS (BB*SS)      // 4096
#define HD (HH*DD)          // 768

typedef __hip_bfloat16 bf16;
typedef __attribute__((ext_vector_type(8))) short short8;
typedef __attribute__((ext_vector_type(4))) float f32x4;

__device__ inline void store_val(float* p, float v) { *p = v; }
__device__ inline void store_val(bf16* p, float v)  { *p = __float2bfloat16(v); }

// ---------------------------------------------------------------------------
// Fused prep: all 6 weight transposes (f32 -> bf16, [R,C] -> [C,R]) PLUS LN1.
// blockIdx.x ranges: Wq [0,576) Wv [576,1152) Wo [1152,1728) W1 [1728,4032)
// W2 [4032,13248) W3 [13248,15552) LN1-rows [15552,19648).
// ---------------------------------------------------------------------------
__global__ __launch_bounds__(256)
void prep_all(const float* __restrict__ Wq, const float* __restrict__ Wv,
              const float* __restrict__ Wo, const float* __restrict__ W1,
              const float* __restrict__ W2, const float* __restrict__ W3,
              bf16* __restrict__ WqT, bf16* __restrict__ WvT,
              bf16* __restrict__ WoT, bf16* __restrict__ W1T,
              bf16* __restrict__ W2T, bf16* __restrict__ W3T,
              const float* __restrict__ x, const float* __restrict__ ln1g,
              const float* __restrict__ ln1b, bf16* __restrict__ xln)
{
    const int id = blockIdx.x;
    const int t = threadIdx.x;

    if (id >= 15552) {                     // ---- LN1 row ----
        const int row = id - 15552;
        const float* xr = x + (size_t)row * EE;
        float v0 = xr[t], v1 = xr[t + 256], v2 = xr[t + 512];
        float s = v0 + v1 + v2;
        #pragma unroll
        for (int off = 32; off > 0; off >>= 1) s += __shfl_xor(s, off);
        __shared__ float red[8];
        const int w = t >> 6;
        if ((t & 63) == 0) red[w] = s;
        __syncthreads();
        const float mean = (red[0] + red[1] + red[2] + red[3]) * (1.f / 768.f);
        float d0 = v0 - mean, d1 = v1 - mean, d2 = v2 - mean;
        float q = d0 * d0 + d1 * d1 + d2 * d2;
        #pragma unroll
        for (int off = 32; off > 0; off >>= 1) q += __shfl_xor(q, off);
        if ((t & 63) == 0) red[4 + w] = q;
        __syncthreads();
        const float var = (red[4] + red[5] + red[6] + red[7]) * (1.f / 768.f);
        const float rstd = rsqrtf(var + 1e-5f);
        bf16* orow = xln + (size_t)row * EE;
        orow[t]       = __float2bfloat16(d0 * rstd * ln1g[t]       + ln1b[t]);
        orow[t + 256] = __float2bfloat16(d1 * rstd * ln1g[t + 256] + ln1b[t + 256]);
        orow[t + 512] = __float2bfloat16(d2 * rstd * ln1g[t + 512] + ln1b[t + 512]);
        return;
    }

    // ---- weight transpose tile ----
    const float* in; bf16* out; int R, C, z = 0, local;
    if (id < 1152) {                       // Wq / Wv: 12 slices of [768, 64]
        const bool isv = id >= 576;
        local = isv ? id - 576 : id;
        in = isv ? Wv : Wq; out = isv ? WvT : WqT;
        R = EE; C = DD;
        z = local / 48; local -= z * 48;
    } else if (id < 1728)  { in = Wo; out = WoT; R = HD; C = EE; local = id - 1152; }
    else if (id < 4032)    { in = W1; out = W1T; R = EE; C = FF; local = id - 1728; }
    else if (id < 13248)   { in = W2; out = W2T; R = FF; C = FF; local = id - 4032; }
    else                   { in = W3; out = W3T; R = FF; C = EE; local = id - 13248; }
    const int tiles_x = C >> 5;
    const int ty = local / tiles_x, tx = local - ty * tiles_x;
    const int r0 = ty * 32, c0 = tx * 32;
    const size_t zoff = (size_t)z * R * C;

    __shared__ float tile[32][33];
    const int lr = t >> 5, lc = t & 31;
    #pragma unroll
    for (int i = 0; i < 4; ++i)
        tile[lr + 8 * i][lc] = in[zoff + (size_t)(r0 + lr + 8 * i) * C + c0 + lc];
    __syncthreads();
    #pragma unroll
    for (int i = 0; i < 4; ++i)
        out[zoff + (size_t)(c0 + lr + 8 * i) * R + r0 + lc] =
            __float2bfloat16(tile[lc][lr + 8 * i]);
}

// ---------------------------------------------------------------------------
// LayerNorm: one block (256 thr) per row of 768; f32 in, OutT out (LN2)
// ---------------------------------------------------------------------------
template<typename OutT>
__global__ __launch_bounds__(256)
void ln_kernel(const float* __restrict__ x, const float* __restrict__ g,
               const float* __restrict__ bt, OutT* __restrict__ o)
{
    const int row = blockIdx.x;
    const float* xr = x + (size_t)row * EE;
    const int t = threadIdx.x;
    float v0 = xr[t], v1 = xr[t + 256], v2 = xr[t + 512];
    float s = v0 + v1 + v2;
    #pragma unroll
    for (int off = 32; off > 0; off >>= 1) s += __shfl_xor(s, off);
    __shared__ float red[8];
    const int w = t >> 6;
    if ((t & 63) == 0) red[w] = s;
    __syncthreads();
    const float mean = (red[0] + red[1] + red[2] + red[3]) * (1.f / 768.f);
    float d0 = v0 - mean, d1 = v1 - mean, d2 = v2 - mean;
    float q = d0 * d0 + d1 * d1 + d2 * d2;
    #pragma unroll
    for (int off = 32; off > 0; off >>= 1) q += __shfl_xor(q, off);
    if ((t & 63) == 0) red[4 + w] = q;
    __syncthreads();
    const float var = (red[4] + red[5] + red[6] + red[7]) * (1.f / 768.f);
    const float rstd = rsqrtf(var + 1e-5f);
    OutT* orow = o + (size_t)row * EE;
    store_val(&orow[t],       d0 * rstd * g[t]       + bt[t]);
    store_val(&orow[t + 256], d1 * rstd * g[t + 256] + bt[t + 256]);
    store_val(&orow[t + 512], d2 * rstd * g[t + 512] + bt[t + 512]);
}

// ---------------------------------------------------------------------------
// bf16 MFMA GEMM (m97 structure), BN-templated: C[M,N] = A @ Bt^T + bias(+res).
// 128xBN tile (BN in {64,128}), BK=64, 4 waves (2x2), wave tile 64x(BN/2).
// XOR swizzle slot = c ^ (row&7) on pre-swizzled GLOBAL source (LDS linear).
// BN=64 doubles the grid for skinny-N GEMMs (O-proj/FF3: 192->384 blocks).
// Per-output-element accumulation order identical across BN (bit-identical).
// ---------------------------------------------------------------------------
template<typename OutT, int BN, bool RELU, bool HAS_RES>
__global__ __launch_bounds__(256, 2)
void mfma_gemm(const bf16* __restrict__ A, const bf16* __restrict__ Bt,
               const float* __restrict__ bias, const float* __restrict__ res,
               OutT* __restrict__ C, int M, int N, int K)
{
    constexpr int NI = BN / 32;            // 16-col frags per wave
    __shared__ bf16 As[128 * 64];
    __shared__ bf16 Bs[BN * 64];
    const int t = threadIdx.x;
    const int lane = t & 63;
    const int w = t >> 6;
    const int wm = w >> 1, wn = w & 1;
    const int m0 = blockIdx.y * 128, n0 = blockIdx.x * BN;
    const int fr = lane & 15;
    const int fq = lane >> 4;

    f32x4 acc[4][NI];
    #pragma unroll
    for (int i = 0; i < 4; ++i)
        #pragma unroll
        for (int j = 0; j < NI; ++j)
            acc[i][j] = (f32x4){0.f, 0.f, 0.f, 0.f};

    for (int k0 = 0; k0 < K; k0 += 64) {
        asm volatile("s_waitcnt lgkmcnt(0)" ::: "memory");
        __syncthreads();
        #pragma unroll
        for (int i = 0; i < 4; ++i) {               // A: 1024 chunks
            const int p = i * 256 + t;
            const int m = p >> 3;
            const int c = (p & 7) ^ (m & 7);
            const bf16* ga = &A[(size_t)(m0 + m) * K + k0 + c * 8];
            __builtin_amdgcn_global_load_lds(
                (const __attribute__((address_space(1))) unsigned int*)ga,
                (__attribute__((address_space(3))) unsigned int*)&As[p * 8], 16, 0, 0);
        }
        #pragma unroll
        for (int i = 0; i < NI; ++i) {              // B: BN*8 chunks
            const int p = i * 256 + t;
            const int m = p >> 3;
            const int c = (p & 7) ^ (m & 7);
            const bf16* gb = &Bt[(size_t)(n0 + m) * K + k0 + c * 8];
            __builtin_amdgcn_global_load_lds(
                (const __attribute__((address_space(1))) unsigned int*)gb,
                (__attribute__((address_space(3))) unsigned int*)&Bs[p * 8], 16, 0, 0);
        }
        asm volatile("s_waitcnt vmcnt(0)" ::: "memory");
        __syncthreads();

        short8 af[4][2], bfr[NI][2];
        #pragma unroll
        for (int mi = 0; mi < 4; ++mi) {
            const int row = wm * 64 + mi * 16 + fr;
            #pragma unroll
            for (int kh = 0; kh < 2; ++kh) {
                const int slot = (kh * 4 + fq) ^ (row & 7);
                af[mi][kh] = *(const short8*)&As[row * 64 + slot * 8];
            }
        }
        #pragma unroll
        for (int ni = 0; ni < NI; ++ni) {
            const int row = wn * (BN / 2) + ni * 16 + fr;
            #pragma unroll
            for (int kh = 0; kh < 2; ++kh) {
                const int slot = (kh * 4 + fq) ^ (row & 7);
                bfr[ni][kh] = *(const short8*)&Bs[row * 64 + slot * 8];
            }
        }
        #pragma unroll
        for (int mi = 0; mi < 4; ++mi)
            #pragma unroll
            for (int ni = 0; ni < NI; ++ni) {
                acc[mi][ni] = __builtin_amdgcn_mfma_f32_16x16x32_bf16(
                    af[mi][0], bfr[ni][0], acc[mi][ni], 0, 0, 0);
                acc[mi][ni] = __builtin_amdgcn_mfma_f32_16x16x32_bf16(
                    af[mi][1], bfr[ni][1], acc[mi][ni], 0, 0, 0);
            }
    }

    // epilogue: C/D layout col=lane&15, row=(lane>>4)*4+reg  [m89/m91]
    #pragma unroll
    for (int ni = 0; ni < NI; ++ni) {
        const int cn = n0 + wn * (BN / 2) + ni * 16 + fr;
        const float bv = bias[cn];
        #pragma unroll
        for (int mi = 0; mi < 4; ++mi) {
            const int rbase = m0 + wm * 64 + mi * 16 + fq * 4;
            #pragma unroll
            for (int j = 0; j < 4; ++j) {
                float v = acc[mi][ni][j] + bv;
                if (HAS_RES) v += res[(size_t)(rbase + j) * N + cn];
                if (RELU) v = fmaxf(v, 0.f);
                store_val(&C[(size_t)(rbase + j) * N + cn], v);
            }
        }
    }
}

// ---------------------------------------------------------------------------
// Fused q+v projection: grid.z selects {WqT,bq -> qbf (row-major)} (z=0) or
// {WvT,bv -> vt [B*H,64,S] transposed} (z=1).
// ---------------------------------------------------------------------------
__global__ __launch_bounds__(256, 2)
void mfma_gemm_qv(const bf16* __restrict__ A,
                  const bf16* __restrict__ Bq, const bf16* __restrict__ Bv,
                  const float* __restrict__ biasq, const float* __restrict__ biasv,
                  bf16* __restrict__ Cq, bf16* __restrict__ Cv)
{
    const int M = BSROWS, N = HD, K = EE;
    const bool isv = (blockIdx.z == 1);
    const bf16* Bt = isv ? Bv : Bq;
    const float* bias = isv ? biasv : biasq;

    __shared__ bf16 As[128 * 64];
    __shared__ bf16 Bs[128 * 64];
    const int t = threadIdx.x;
    const int lane = t & 63;
    const int w = t >> 6;
    const int wm = w >> 1, wn = w & 1;
    const int m0 = blockIdx.y * 128, n0 = blockIdx.x * 128;
    const int fr = lane & 15;
    const int fq = lane >> 4;

    f32x4 acc[4][4];
    #pragma unroll
    for (int i = 0; i < 4; ++i)
        #pragma unroll
        for (int j = 0; j < 4; ++j)
            acc[i][j] = (f32x4){0.f, 0.f, 0.f, 0.f};

    for (int k0 = 0; k0 < K; k0 += 64) {
        asm volatile("s_waitcnt lgkmcnt(0)" ::: "memory");
        __syncthreads();
        #pragma unroll
        for (int i = 0; i < 4; ++i) {
            const int p = (w * 4 + i) * 64 + lane;
            const int m = p >> 3;
            const int c = (p & 7) ^ (m & 7);
            const bf16* ga = &A [(size_t)(m0 + m) * K + k0 + c * 8];
            const bf16* gb = &Bt[(size_t)(n0 + m) * K + k0 + c * 8];
            bf16* la = &As[(size_t)(w * 4 + i) * 512];
            bf16* lb = &Bs[(size_t)(w * 4 + i) * 512];
            __builtin_amdgcn_global_load_lds(
                (const __attribute__((address_space(1))) unsigned int*)ga,
                (__attribute__((address_space(3))) unsigned int*)la, 16, 0, 0);
            __builtin_amdgcn_global_load_lds(
                (const __attribute__((address_space(1))) unsigned int*)gb,
                (__attribute__((address_space(3))) unsigned int*)lb, 16, 0, 0);
        }
        asm volatile("s_waitcnt vmcnt(0)" ::: "memory");
        __syncthreads();

        short8 af[4][2], bfr[4][2];
        #pragma unroll
        for (int mi = 0; mi < 4; ++mi) {
            const int row = wm * 64 + mi * 16 + fr;
            #pragma unroll
            for (int kh = 0; kh < 2; ++kh) {
                const int slot = (kh * 4 + fq) ^ (row & 7);
                af[mi][kh] = *(const short8*)&As[row * 64 + slot * 8];
            }
        }
        #pragma unroll
        for (int ni = 0; ni < 4; ++ni) {
            const int row = wn * 64 + ni * 16 + fr;
            #pragma unroll
            for (int kh = 0; kh < 2; ++kh) {
                const int slot = (kh * 4 + fq) ^ (row & 7);
                bfr[ni][kh] = *(const short8*)&Bs[row * 64 + slot * 8];
            }
        }
        #pragma unroll
        for (int mi = 0; mi < 4; ++mi)
            #pragma unroll
            for (int ni = 0; ni < 4; ++ni) {
                acc[mi][ni] = __builtin_amdgcn_mfma_f32_16x16x32_bf16(
                    af[mi][0], bfr[ni][0], acc[mi][ni], 0, 0, 0);
                acc[mi][ni] = __builtin_amdgcn_mfma_f32_16x16x32_bf16(
                    af[mi][1], bfr[ni][1], acc[mi][ni], 0, 0, 0);
            }
    }

    #pragma unroll
    for (int ni = 0; ni < 4; ++ni) {
        const int cn = n0 + wn * 64 + ni * 16 + fr;
        const float bv = bias[cn];
        #pragma unroll
        for (int mi = 0; mi < 4; ++mi) {
            const int rbase = m0 + wm * 64 + mi * 16 + fq * 4;
            if (isv) {
                const int bidx = rbase >> 11, sidx = rbase & (SS - 1);
                const int hh = cn >> 6, dd = cn & 63;
                alignas(8) bf16 tmp[4];
                #pragma unroll
                for (int j = 0; j < 4; ++j)
                    tmp[j] = __float2bfloat16(acc[mi][ni][j] + bv);
                *(ushort4*)(Cv + (((size_t)(bidx * HH + hh) * 64 + dd) * SS + sidx))
                    = *(const ushort4*)tmp;
            } else {
                #pragma unroll
                for (int j = 0; j < 4; ++j)
                    Cq[(size_t)(rbase + j) * N + cn]
                        = __float2bfloat16(acc[mi][ni][j] + bv);
            }
        }
    }
}

// ---------------------------------------------------------------------------
// MFMA flash attention, PAIRED-qt load balance. Block pr handles qt=31-pr
// then qt=pr (33 kv-tiles per pair -> 384 uniform blocks). Single-buffered
// KVBLK=64, l via ones-MFMA. q layout [B*S, HD] bf16 (k = q, source bug);
// vt [B*H, 64(d), S]. Causal + input_mask; all-masked row -> diag p=1 at
// final tile (=> out = v[row], matches reference).
// ---------------------------------------------------------------------------
__global__ __launch_bounds__(256, 2)
void attn_mfma(const bf16* __restrict__ qg, const bf16* __restrict__ vtg,
               const int* __restrict__ maskg, bf16* __restrict__ outg)
{
    const int pr = blockIdx.x;   // 0..15
    const int h  = blockIdx.y;
    const int b  = blockIdx.z;
    __shared__ bf16 Ks[64 * 64];   // XOR-swizzled K rows (= q rows)
    __shared__ bf16 Vts[64 * 64];  // XOR-swizzled Vt rows [d][kv]
    __shared__ bf16 Ps[64][72];    // P row-major [q][kv] (wave-local rows)
    const int t = threadIdx.x;
    const int lane = t & 63;
    const int w = t >> 6;
    const int fr = lane & 15;
    const int g  = lane >> 4;

    short8 ones;
    #pragma unroll
    for (int i = 0; i < 8; ++i) ones[i] = (short)0x3F80;

    for (int half = 0; half < 2; ++half) {
        const int qt = half == 0 ? (31 - pr) : pr;   // big tile first
        const int q0 = qt * 64;

        asm volatile("s_waitcnt lgkmcnt(0)" ::: "memory");
        __syncthreads();

        #pragma unroll
        for (int i = 0; i < 2; ++i) {
            const int pc = i * 256 + t;
            const int m = pc >> 3, c = (pc & 7) ^ (m & 7);
            const bf16* src = qg + ((size_t)(b * SS + q0 + m) * HD + h * 64 + c * 8);
            __builtin_amdgcn_global_load_lds(
                (const __attribute__((address_space(1))) unsigned int*)src,
                (__attribute__((address_space(3))) unsigned int*)&Ks[pc * 8], 16, 0, 0);
        }
        asm volatile("s_waitcnt vmcnt(0)" ::: "memory");
        __syncthreads();
        short8 qa[2];
        {
            const int row = w * 16 + fr;
            #pragma unroll
            for (int s = 0; s < 2; ++s) {
                const int slot = (s * 4 + g) ^ (row & 7);
                qa[s] = *(const short8*)&Ks[row * 64 + slot * 8];
            }
        }

        f32x4 o_acc[4];
        #pragma unroll
        for (int i = 0; i < 4; ++i) o_acc[i] = (f32x4){0.f, 0.f, 0.f, 0.f};
        f32x4 acc_l = (f32x4){0.f, 0.f, 0.f, 0.f};
        float run_m[4];
        #pragma unroll
        for (int j = 0; j < 4; ++j) run_m[j] = -INFINITY;

        for (int kvt = 0; kvt <= qt; ++kvt) {
            const int kv0 = kvt * 64;
            asm volatile("s_waitcnt lgkmcnt(0)" ::: "memory");
            __syncthreads();
            #pragma unroll
            for (int i = 0; i < 2; ++i) {
                const int pc = i * 256 + t;
                const int m = pc >> 3, c = (pc & 7) ^ (m & 7);
                const bf16* ksrc = qg  + ((size_t)(b * SS + kv0 + m) * HD + h * 64 + c * 8);
                const bf16* vsrc = vtg + (((size_t)(b * HH + h) * 64 + m) * SS + kv0 + c * 8);
                __builtin_amdgcn_global_load_lds(
                    (const __attribute__((address_space(1))) unsigned int*)ksrc,
                    (__attribute__((address_space(3))) unsigned int*)&Ks[pc * 8], 16, 0, 0);
                __builtin_amdgcn_global_load_lds(
                    (const __attribute__((address_space(1))) unsigned int*)vsrc,
                    (__attribute__((address_space(3))) unsigned int*)&Vts[pc * 8], 16, 0, 0);
            }
            int mv[4];
            #pragma unroll
            for (int ni = 0; ni < 4; ++ni)
                mv[ni] = maskg[b * SS + kv0 + ni * 16 + fr];
            asm volatile("s_waitcnt vmcnt(0)" ::: "memory");
            __syncthreads();

            // ---- QK^T ----
            f32x4 acc_s[4];
            #pragma unroll
            for (int ni = 0; ni < 4; ++ni) acc_s[ni] = (f32x4){0.f, 0.f, 0.f, 0.f};
            __builtin_amdgcn_s_setprio(1);
            #pragma unroll
            for (int ni = 0; ni < 4; ++ni) {
                const int row = ni * 16 + fr;
                #pragma unroll
                for (int s = 0; s < 2; ++s) {
                    const int slot = (s * 4 + g) ^ (row & 7);
                    short8 kb = *(const short8*)&Ks[row * 64 + slot * 8];
                    acc_s[ni] = __builtin_amdgcn_mfma_f32_16x16x32_bf16(
                        qa[s], kb, acc_s[ni], 0, 0, 0);
                }
            }
            __builtin_amdgcn_s_setprio(0);

            // ---- masked online softmax ----
            float sv[4][4], mj[4], alpha[4];
            #pragma unroll
            for (int j = 0; j < 4; ++j) mj[j] = -INFINITY;
            #pragma unroll
            for (int ni = 0; ni < 4; ++ni) {
                const int kvcol = kv0 + ni * 16 + fr;
                const bool mok = (mv[ni] != 0);
                #pragma unroll
                for (int j = 0; j < 4; ++j) {
                    const int qrow = q0 + w * 16 + g * 4 + j;
                    const bool valid = mok && (kvcol <= qrow);
                    const float s = valid ? acc_s[ni][j] * 0.125f : -INFINITY;
                    sv[ni][j] = s;
                    mj[j] = fmaxf(mj[j], s);
                }
            }
            #pragma unroll
            for (int j = 0; j < 4; ++j) {
                #pragma unroll
                for (int off = 1; off < 16; off <<= 1)
                    mj[j] = fmaxf(mj[j], __shfl_xor(mj[j], off));
                const float newm = fmaxf(run_m[j], mj[j]);
                const float al = (newm == -INFINITY) ? 1.f : __expf(run_m[j] - newm);
                #pragma unroll
                for (int ni = 0; ni < 4; ++ni) {
                    float pv = (sv[ni][j] == -INFINITY) ? 0.f : __expf(sv[ni][j] - newm);
                    if (kvt == qt && newm == -INFINITY) {
                        const int dloc = w * 16 + g * 4 + j;   // diag: kv==qrow
                        if ((dloc >> 4) == ni && (dloc & 15) == fr) pv = 1.f;
                    }
                    sv[ni][j] = pv;
                }
                run_m[j] = newm;
                alpha[j] = al;
            }
            #pragma unroll
            for (int ni = 0; ni < 4; ++ni)
                #pragma unroll
                for (int j = 0; j < 4; ++j)
                    Ps[w * 16 + g * 4 + j][ni * 16 + fr] = __float2bfloat16(sv[ni][j]);
            #pragma unroll
            for (int nt = 0; nt < 4; ++nt)
                #pragma unroll
                for (int j = 0; j < 4; ++j)
                    o_acc[nt][j] *= alpha[j];
            #pragma unroll
            for (int j = 0; j < 4; ++j) acc_l[j] *= alpha[j];

            // ---- PV + l-sum ----
            short8 pa[2];
            #pragma unroll
            for (int s = 0; s < 2; ++s)
                pa[s] = *(const short8*)&Ps[w * 16 + fr][s * 32 + g * 8];
            __builtin_amdgcn_s_setprio(1);
            #pragma unroll
            for (int nt = 0; nt < 4; ++nt) {
                const int row = nt * 16 + fr;
                #pragma unroll
                for (int s = 0; s < 2; ++s) {
                    const int slot = (s * 4 + g) ^ (row & 7);
                    short8 vb = *(const short8*)&Vts[row * 64 + slot * 8];
                    o_acc[nt] = __builtin_amdgcn_mfma_f32_16x16x32_bf16(
                        pa[s], vb, o_acc[nt], 0, 0, 0);
                }
            }
            #pragma unroll
            for (int s = 0; s < 2; ++s)
                acc_l = __builtin_amdgcn_mfma_f32_16x16x32_bf16(
                    pa[s], ones, acc_l, 0, 0, 0);
            __builtin_amdgcn_s_setprio(0);
        }

        float inv[4];
        #pragma unroll
        for (int j = 0; j < 4; ++j) inv[j] = (acc_l[j] > 0.f) ? 1.f / acc_l[j] : 0.f;
        #pragma unroll
        for (int nt = 0; nt < 4; ++nt)
            #pragma unroll
            for (int j = 0; j < 4; ++j)
                outg[(size_t)(b * SS + q0 + w * 16 + g * 4 + j) * HD + h * 64 + nt * 16 + fr]
                    = __float2bfloat16(o_acc[nt][j] * inv[j]);
    }
}

// ---------------------------------------------------------------------------
extern "C" void kernel_launch(void* const* d_in, const int* in_sizes, int n_in,
                              void* d_out, int out_size, void* d_ws, size_t ws_size,
                              hipStream_t stream)
{
    const float* x    = (const float*)d_in[0];
    const float* Wq   = (const float*)d_in[1];
    const float* bq   = (const float*)d_in[2];
    const float* Wv   = (const float*)d_in[3];
    const float* bv   = (const float*)d_in[4];
    const float* Wo   = (const float*)d_in[5];
    const float* bo   = (const float*)d_in[6];
    const float* ln1g = (const float*)d_in[7];
    const float* ln1b = (const float*)d_in[8];
    const float* W1   = (const float*)d_in[9];
    const float* b1   = (const float*)d_in[10];
    const float* W2   = (const float*)d_in[11];
    const float* b2   = (const float*)d_in[12];
    const float* W3   = (const float*)d_in[13];
    const float* b3   = (const float*)d_in[14];
    const float* ln2g = (const float*)d_in[15];
    const float* ln2b = (const float*)d_in[16];
    const int*   mask = (const int*)d_in[17];
    float* out = (float*)d_out;
    char* wsb  = (char*)d_ws;

    // workspace (~96.4 MB). Liveness aliasing: h1 (25.2MB) overlays
    // [qbf|vt|attno|pad] (all dead by FF1); xln reused as y1ln.
    size_t off = 0;
    bf16* WqT = (bf16*)(wsb + off); off += (size_t)EE * HD * 2;
    bf16* WvT = (bf16*)(wsb + off); off += (size_t)EE * HD * 2;
    bf16* WoT = (bf16*)(wsb + off); off += (size_t)HD * EE * 2;
    bf16* W1T = (bf16*)(wsb + off); off += (size_t)EE * FF * 2;
    bf16* W3T = (bf16*)(wsb + off); off += (size_t)FF * EE * 2;
    bf16* W2T = (bf16*)(wsb + off); off += (size_t)FF * FF * 2;
    bf16* qbf = (bf16*)(wsb + off);
    bf16* h1  = qbf;                  off += (size_t)BSROWS * HD * 2;
    bf16* vt  = (bf16*)(wsb + off);   off += (size_t)BSROWS * HD * 2;
    bf16* attno = (bf16*)(wsb + off); off += (size_t)BSROWS * HD * 2;
    /* pad for h1 tail */             off += (size_t)BSROWS * HD * 2;
    bf16* xln = (bf16*)(wsb + off);   off += (size_t)BSROWS * EE * 2;
    bf16* h2  = (bf16*)(wsb + off);   off += (size_t)BSROWS * FF * 2;
    float* y1 = (float*)(wsb + off);  off += (size_t)BSROWS * EE * 4;

    // 1. weight transposes + LN1 fused in one dispatch
    prep_all<<<15552 + BSROWS, 256, 0, stream>>>(
        Wq, Wv, Wo, W1, W2, W3, WqT, WvT, WoT, W1T, W2T, W3T,
        x, ln1g, ln1b, xln);
    // 2. fused q+v projection: z=0 -> qbf, z=1 -> vt [B*H, 64, S]
    dim3 gp(HD / 128, BSROWS / 128);
    mfma_gemm_qv<<<dim3(gp.x, gp.y, 2), 256, 0, stream>>>(
        xln, WqT, WvT, bq, bv, qbf, vt);
    // 3. MFMA flash attention (paired qt) -> attno (bf16)
    attn_mfma<<<dim3(SS/128, HH, BB), 256, 0, stream>>>(qbf, vt, mask, attno);
    // 4. O-proj + residual x -> y1 (f32)  [BN=64: 384 blocks, 2x fill]
    dim3 go(EE / 64, BSROWS / 128);
    mfma_gemm<float, 64, false, true><<<go, 256, 0, stream>>>(attno, WoT, bo, x, y1, BSROWS, EE, HD);
    // 5. LN2: y1 -> y1ln (reuse xln)
    bf16* y1ln = xln;
    ln_kernel<bf16><<<BSROWS, 256, 0, stream>>>(y1, ln2g, ln2b, y1ln);
    // 6. FF1: h1 = relu(y1ln @ W1 + b1)   [m97 128x128]
    dim3 gf(FF / 128, BSROWS / 128);
    mfma_gemm<bf16, 128, true, false><<<gf, 256, 0, stream>>>(y1ln, W1T, b1, nullptr, h1, BSROWS, FF, EE);
    // 7. FF2: h2 = relu(h1 @ W2 + b2)     [m97 128x128]
    mfma_gemm<bf16, 128, true, false><<<gf, 256, 0, stream>>>(h1, W2T, b2, nullptr, h2, BSROWS, FF, FF);
    // 8. FF3: out = h2 @ W3 + b3 + y1     [BN=64: 384 blocks, 2x fill]
    mfma_gemm<float, 64, false, true><<<go, 256, 0, stream>>>(h2, W3T, b3, y1, out, BSROWS, EE, FF);
}